// Round 9
// baseline (189.484 us; speedup 1.0000x reference)
//
#include <hip/hip_runtime.h>
#include <hip/hip_bf16.h>

#define NB 32
#define CD 256
#define SS 1024
#define DD 256
#define TT 512
// SCALE * log2(e): softmax computed in base-2
#define QSCALE 0.09016844f

typedef __attribute__((ext_vector_type(8))) short s16x8;
typedef __attribute__((ext_vector_type(4))) short s16x4;
typedef __attribute__((ext_vector_type(4))) float f32x4;
typedef __attribute__((ext_vector_type(16))) float f32x16;
typedef __attribute__((ext_vector_type(4))) unsigned int u32x4;

__device__ __forceinline__ unsigned short f2bf(float f) {
  unsigned u = __builtin_bit_cast(unsigned, f);
  u = (u + 0x7FFFu + ((u >> 16) & 1u)) >> 16;
  return (unsigned short)u;
}
__device__ __forceinline__ float bf2f(unsigned short h) {
  return __builtin_bit_cast(float, ((unsigned)h) << 16);
}
__device__ __forceinline__ unsigned pk2(float a, float b) {
  float2 f2; f2.x = a; f2.y = b;
  __hip_bfloat162 h = __float22bfloat162_rn(f2);
  unsigned u;
  __builtin_memcpy(&u, &h, 4);
  return u;
}
__device__ __forceinline__ float asf(unsigned u) {
  return __builtin_bit_cast(float, u);
}
#define GLOAD16(gp, lp)                                                        \
  __builtin_amdgcn_global_load_lds(                                            \
      (const __attribute__((address_space(1))) unsigned int*)(const void*)(gp),\
      (__attribute__((address_space(3))) unsigned int*)(void*)(lp), 16, 0, 0)

// ---- misc: blocks 0..1023 = weight fp32->bf16; 1024..1055 = temb ----
__global__ __launch_bounds__(256) void k_misc(const float* __restrict__ t,
    const float* __restrict__ Wt, const float* __restrict__ bt, float* __restrict__ temb,
    const float* __restrict__ wq, const float* __restrict__ wk,
    const float* __restrict__ wv, const float* __restrict__ wp,
    unsigned short* __restrict__ dst) {
  const int b = blockIdx.x;
  if (b < 1024) {
    const int i = b * 256 + threadIdx.x;
    const int which = i >> 16, off = i & 65535;
    const float* s = which == 0 ? wq : which == 1 ? wk : which == 2 ? wv : wp;
    dst[i] = f2bf(s[off]);
  } else {
    const int n = b - 1024, c = threadIdx.x;
    const float4* tv = (const float4*)(t + (size_t)n * TT);
    const float4* wvv = (const float4*)(Wt + (size_t)c * TT);
    float acc = 0.f;
#pragma unroll 8
    for (int i = 0; i < TT / 4; ++i) {
      float4 a = tv[i], bb = wvv[i];
      acc += a.x * bb.x + a.y * bb.y + a.z * bb.z + a.w * bb.w;
    }
    acc += bt[c];
    temb[n * CD + c] = fmaxf(acc, 0.f);
  }
}

// ---- xb[n, s, c] = bf16(x[n,c,s] + temb[n,c]) ----
__global__ __launch_bounds__(256) void k_addT(const float* __restrict__ x,
    const float* __restrict__ temb, unsigned short* __restrict__ xb) {
  __shared__ float tile[32][33];
  const int tx = threadIdx.x & 31, ty = threadIdx.x >> 5;
  const int n = blockIdx.z, s0 = blockIdx.y * 32, c0 = blockIdx.x * 32;
#pragma unroll
  for (int i = 0; i < 4; ++i) {
    const int cc = ty + i * 8;
    tile[cc][tx] = x[((size_t)n * CD + c0 + cc) * SS + s0 + tx] + temb[n * CD + c0 + cc];
  }
  __syncthreads();
  unsigned short* op = xb + ((size_t)n * SS + s0) * CD + c0;
#pragma unroll
  for (int i = 0; i < 4; ++i) {
    const int ss = ty + i * 8;
    op[(size_t)ss * CD + tx] = f2bf(tile[tx][ss]);
  }
}

// ---- QKV GEMM: z = which*32 + n. which==2 writes V transposed. ----
__global__ __launch_bounds__(256) void k_qkv(const unsigned short* __restrict__ A,
    const unsigned short* __restrict__ wb, unsigned short* __restrict__ qb,
    unsigned short* __restrict__ kb, unsigned short* __restrict__ vtb) {
  __shared__ __attribute__((aligned(16))) unsigned short As[128 * 32];
  __shared__ __attribute__((aligned(16))) unsigned short Bs[128 * 32];
  const int which = blockIdx.z >> 5, n = blockIdx.z & 31;
  const int s0 = blockIdx.x * 128;
  const int d0 = blockIdx.y * 128;
  const unsigned short* B = wb + which * 65536;
  const int tid = threadIdx.x;
  const int lane = tid & 63, wid = tid >> 6;
  const int lo = lane & 15, hi = lane >> 4;
  const int wr = wid >> 1, wc = wid & 1;
  const unsigned short* An = A + (size_t)n * SS * CD;
  f32x4 acc[4][4] = {};
  for (int k0 = 0; k0 < CD; k0 += 32) {
#pragma unroll
    for (int i = 0; i < 2; ++i) {
      const int seg = i * 256 + wid * 64 + lane;
      const int row = seg >> 2, c8 = seg & 3;
      GLOAD16(An + (size_t)(s0 + row) * CD + k0 + c8 * 8, As + (size_t)(i * 256 + wid * 64) * 8);
      GLOAD16(B + (size_t)(d0 + row) * CD + k0 + c8 * 8, Bs + (size_t)(i * 256 + wid * 64) * 8);
    }
    __syncthreads();
    s16x8 a[4], b[4];
#pragma unroll
    for (int mi = 0; mi < 4; ++mi)
      a[mi] = *(const s16x8*)&As[(wr * 64 + mi * 16 + lo) * 32 + hi * 8];
#pragma unroll
    for (int ni = 0; ni < 4; ++ni)
      b[ni] = *(const s16x8*)&Bs[(wc * 64 + ni * 16 + lo) * 32 + hi * 8];
#pragma unroll
    for (int mi = 0; mi < 4; ++mi)
#pragma unroll
      for (int ni = 0; ni < 4; ++ni)
        acc[mi][ni] = __builtin_amdgcn_mfma_f32_16x16x32_bf16(a[mi], b[ni], acc[mi][ni], 0, 0, 0);
    __syncthreads();
  }
  if (which < 2) {
    const float osc = which == 0 ? QSCALE : 1.0f;
    unsigned short* On = (which == 0 ? qb : kb) + (size_t)n * SS * DD;
#pragma unroll
    for (int mi = 0; mi < 4; ++mi) {
      const int r0 = s0 + wr * 64 + mi * 16 + hi * 4;
#pragma unroll
      for (int ni = 0; ni < 4; ++ni) {
        const int col = d0 + wc * 64 + ni * 16 + lo;
#pragma unroll
        for (int r = 0; r < 4; ++r)
          On[(size_t)(r0 + r) * DD + col] = f2bf(acc[mi][ni][r] * osc);
      }
    }
  } else {
    unsigned short* On = vtb + (size_t)n * DD * SS;
#pragma unroll
    for (int mi = 0; mi < 4; ++mi) {
      const int r0 = s0 + wr * 64 + mi * 16 + hi * 4;
#pragma unroll
      for (int ni = 0; ni < 4; ++ni) {
        const int col = d0 + wc * 64 + ni * 16 + lo;
        s16x4 v;
#pragma unroll
        for (int r = 0; r < 4; ++r) v[r] = (short)f2bf(acc[mi][ni][r]);
        *(s16x4*)&On[(size_t)col * SS + r0] = v;
      }
    }
  }
}

// ---- flash attention, swapped 32x32 MFMA, fully in-register softmax+P
// (permlane32_swap builtin). grid 512 with n->XCD swizzle (xcd=bid&7).
// 4 waves x 32 q-rows; lane owns q=lane&31. K/V^T dbuf in LDS (KVBLK=32,
// XOR-swizzled, linear dest + pre-swizzled source). 48KB LDS, 3 blocks/CU. ----
__global__ __launch_bounds__(256, 3) void k_attn(const unsigned short* __restrict__ qb,
    const unsigned short* __restrict__ kb, const unsigned short* __restrict__ vtb,
    unsigned short* __restrict__ ob) {
  // ushort elems: Ks[2][8192] @0, Vs[2][4096] @16384  => 48KB
  __shared__ __attribute__((aligned(16))) unsigned short lds[24576];
  const int bid = blockIdx.x;
  const int xcd = bid & 7, inner = bid >> 3;
  const int n = xcd + ((inner >> 4) << 3);
  const int sub = inner & 15;
  const int qt = sub & 7, dh = sub >> 3;
  const int tid = threadIdx.x, lane = tid & 63, w = tid >> 6;
  const int l31 = lane & 31, h = lane >> 5;
  const int dblk = dh * 128;
  const unsigned short* Kn = kb + (size_t)n * SS * DD;
  const unsigned short* Vn = vtb + ((size_t)n * DD + dblk) * SS;
  const int qrow = qt * 128 + w * 32 + l31;

  const unsigned short* Qp = qb + ((size_t)n * SS + qrow) * DD + h * 8;
  s16x8 qf[16];
#pragma unroll
  for (int ks = 0; ks < 16; ++ks) qf[ks] = *(const s16x8*)(Qp + ks * 16);

  f32x16 acc[4] = {};
  float mrun = -3.0e38f, lrun = 0.f;

  auto STAGE = [&](int buf, int jt) {
    const int j0 = jt * 32;
    unsigned short* KsB = lds + buf * 8192;
    unsigned short* VsB = lds + 16384 + buf * 4096;
#pragma unroll
    for (int i = 0; i < 4; ++i) {  // K: 32 rows x 256 cols
      const int idx = i * 256 + w * 64 + lane;
      const int row = idx >> 5, c8 = idx & 31;
      GLOAD16(Kn + (size_t)(j0 + row) * DD + ((c8 ^ (row & 7)) << 3),
              KsB + (size_t)(i * 256 + w * 64) * 8);
    }
#pragma unroll
    for (int i = 0; i < 2; ++i) {  // V^T: 128 d-rows x 32 j-cols
      const int idx = i * 256 + w * 64 + lane;
      const int row = idx >> 2, c8 = idx & 3;
      GLOAD16(Vn + (size_t)row * SS + j0 + ((c8 ^ ((row >> 1) & 3)) << 3),
              VsB + (size_t)(i * 256 + w * 64) * 8);
    }
  };

  STAGE(0, 0);
  __syncthreads();

  int cur = 0;
#pragma unroll 1
  for (int jt = 0; jt < 32; ++jt) {
    if (jt + 1 < 32) STAGE(cur ^ 1, jt + 1);
    const unsigned short* Ks = lds + cur * 8192;
    const unsigned short* Vs = lds + 16384 + cur * 4096;
    // ---- QK^T (swapped): lane holds S[j=crow(r,h)][q=l31], crow=(r&3)+8*(r>>2)+4h
    f32x16 sc = {};
    __builtin_amdgcn_s_setprio(1);
#pragma unroll
    for (int ks = 0; ks < 16; ++ks) {
      const s16x8 kf = *(const s16x8*)&Ks[l31 * 256 + ((((ks * 2 + h)) ^ (l31 & 7)) << 3)];
      sc = __builtin_amdgcn_mfma_f32_32x32x16_bf16(kf, qf[ks], sc, 0, 0, 0);
    }
    __builtin_amdgcn_s_setprio(0);
    // ---- online softmax in base-2; pair {lane, lane^32} via permlane swap ----
    float pm = fmaxf(fmaxf(fmaxf(sc[0], sc[1]), fmaxf(sc[2], sc[3])),
                     fmaxf(fmaxf(sc[4], sc[5]), fmaxf(sc[6], sc[7])));
    pm = fmaxf(pm, fmaxf(fmaxf(fmaxf(sc[8], sc[9]), fmaxf(sc[10], sc[11])),
                         fmaxf(fmaxf(sc[12], sc[13]), fmaxf(sc[14], sc[15]))));
    {
      auto rp = __builtin_amdgcn_permlane32_swap(__builtin_bit_cast(unsigned, pm),
                                                 __builtin_bit_cast(unsigned, pm), false, false);
      pm = fmaxf(asf(rp[0]), asf(rp[1]));
    }
    if (__any(pm > mrun + 8.f)) {
      const float mn = fmaxf(mrun, pm);
      const float corr = exp2f(mrun - mn);
      mrun = mn; lrun *= corr;
#pragma unroll
      for (int dc = 0; dc < 4; ++dc)
#pragma unroll
        for (int i = 0; i < 16; ++i) acc[dc][i] *= corr;
    }
#pragma unroll
    for (int i = 0; i < 16; ++i) sc[i] = exp2f(sc[i] - mrun);
    lrun += (((sc[0] + sc[1]) + (sc[2] + sc[3])) + ((sc[4] + sc[5]) + (sc[6] + sc[7]))) +
            (((sc[8] + sc[9]) + (sc[10] + sc[11])) + ((sc[12] + sc[13]) + (sc[14] + sc[15])));
    // ---- P -> A-fragments fully in-register.
    // wv0=j{0,1}/{4,5}, wv1=j{2,3}/{6,7}, wv2=j{8,9}/{12,13}, wv3=j{10,11}/{14,15}
    // swap(a,b): a.hi<->b.lo => word0=swap(wv0,wv2)[0], word2=[1]; word1/3 from (wv1,wv3).
    const unsigned wv0 = pk2(sc[0], sc[1]),   wv1 = pk2(sc[2], sc[3]);
    const unsigned wv2 = pk2(sc[4], sc[5]),   wv3 = pk2(sc[6], sc[7]);
    const unsigned wv4 = pk2(sc[8], sc[9]),   wv5 = pk2(sc[10], sc[11]);
    const unsigned wv6 = pk2(sc[12], sc[13]), wv7 = pk2(sc[14], sc[15]);
    auto r02 = __builtin_amdgcn_permlane32_swap(wv0, wv2, false, false);
    auto r13 = __builtin_amdgcn_permlane32_swap(wv1, wv3, false, false);
    auto r46 = __builtin_amdgcn_permlane32_swap(wv4, wv6, false, false);
    auto r57 = __builtin_amdgcn_permlane32_swap(wv5, wv7, false, false);
    const u32x4 pa0u = {r02[0], r13[0], r02[1], r13[1]};
    const u32x4 pa1u = {r46[0], r57[0], r46[1], r57[1]};
    const s16x8 pa0 = __builtin_bit_cast(s16x8, pa0u);
    const s16x8 pa1 = __builtin_bit_cast(s16x8, pa1u);
    // ---- PV from Vs[cur] ----
    __builtin_amdgcn_s_setprio(1);
#pragma unroll
    for (int dc = 0; dc < 4; ++dc) {
      const s16x8 vf0 = *(const s16x8*)&Vs[(dc * 32 + l31) * 32 + ((h ^ ((l31 >> 1) & 3)) << 3)];
      acc[dc] = __builtin_amdgcn_mfma_f32_32x32x16_bf16(vf0, pa0, acc[dc], 0, 0, 0);
    }
#pragma unroll
    for (int dc = 0; dc < 4; ++dc) {
      const s16x8 vf1 = *(const s16x8*)&Vs[(dc * 32 + l31) * 32 + (((2 + h) ^ ((l31 >> 1) & 3)) << 3)];
      acc[dc] = __builtin_amdgcn_mfma_f32_32x32x16_bf16(vf1, pa1, acc[dc], 0, 0, 0);
    }
    __builtin_amdgcn_s_setprio(0);
    __syncthreads();  // drains vmcnt(0): next tile staged; waves past cur
    cur ^= 1;
  }
  {
    auto rl = __builtin_amdgcn_permlane32_swap(__builtin_bit_cast(unsigned, lrun),
                                               __builtin_bit_cast(unsigned, lrun), false, false);
    lrun = asf(rl[0]) + asf(rl[1]);
  }
  const float inv = 1.0f / lrun;
  unsigned short* Op = ob + ((size_t)n * SS + qrow) * DD + dblk;
#pragma unroll
  for (int dc = 0; dc < 4; ++dc)
#pragma unroll
    for (int rg = 0; rg < 4; ++rg) {
      uint2 u;
      u.x = pk2(acc[dc][rg * 4 + 0] * inv, acc[dc][rg * 4 + 1] * inv);
      u.y = pk2(acc[dc][rg * 4 + 2] * inv, acc[dc][rg * 4 + 3] * inv);
      *(uint2*)(Op + dc * 32 + rg * 8 + h * 4) = u;
    }
}

// ---- fused proj + bias + residual ----
__global__ __launch_bounds__(256) void k_proj(const unsigned short* __restrict__ ob,
    const unsigned short* __restrict__ wpb, const float* __restrict__ bp,
    const float* __restrict__ x, float* __restrict__ out) {
  __shared__ __attribute__((aligned(16))) unsigned short As[128 * 32];
  __shared__ __attribute__((aligned(16))) unsigned short Bs[128 * 32];
  const int n = blockIdx.z;
  const int s0 = blockIdx.x * 128;
  const int c0 = blockIdx.y * 128;
  const int tid = threadIdx.x;
  const int lane = tid & 63, wid = tid >> 6;
  const int lo = lane & 15, hi = lane >> 4;
  const int wr = wid >> 1, wc = wid & 1;
  const unsigned short* On = ob + (size_t)n * SS * DD;
  f32x4 acc[4][4] = {};
  for (int k0 = 0; k0 < DD; k0 += 32) {
#pragma unroll
    for (int i = 0; i < 2; ++i) {
      const int seg = i * 256 + wid * 64 + lane;
      const int row = seg >> 2, c8 = seg & 3;
      GLOAD16(wpb + (size_t)(c0 + row) * DD + k0 + c8 * 8, As + (size_t)(i * 256 + wid * 64) * 8);
      GLOAD16(On + (size_t)(s0 + row) * DD + k0 + c8 * 8, Bs + (size_t)(i * 256 + wid * 64) * 8);
    }
    __syncthreads();
    s16x8 a[4], b[4];
#pragma unroll
    for (int mi = 0; mi < 4; ++mi)
      a[mi] = *(const s16x8*)&As[(wr * 64 + mi * 16 + lo) * 32 + hi * 8];
#pragma unroll
    for (int ni = 0; ni < 4; ++ni)
      b[ni] = *(const s16x8*)&Bs[(wc * 64 + ni * 16 + lo) * 32 + hi * 8];
#pragma unroll
    for (int mi = 0; mi < 4; ++mi)
#pragma unroll
      for (int ni = 0; ni < 4; ++ni)
        acc[mi][ni] = __builtin_amdgcn_mfma_f32_16x16x32_bf16(a[mi], b[ni], acc[mi][ni], 0, 0, 0);
    __syncthreads();
  }
#pragma unroll
  for (int mi = 0; mi < 4; ++mi) {
#pragma unroll
    for (int r = 0; r < 4; ++r) {
      const int c = c0 + wr * 64 + mi * 16 + hi * 4 + r;
      const float bpc = bp[c];
      const size_t base = ((size_t)n * CD + c) * SS;
#pragma unroll
      for (int ni = 0; ni < 4; ++ni) {
        const int s = s0 + wc * 64 + ni * 16 + lo;
        out[base + s] = acc[mi][ni][r] + bpc + x[base + s];
      }
    }
  }
}

extern "C" void kernel_launch(void* const* d_in, const int* in_sizes, int n_in,
                              void* d_out, int out_size, void* d_ws, size_t ws_size,
                              hipStream_t stream) {
  const float* x  = (const float*)d_in[0];
  const float* t  = (const float*)d_in[1];
  const float* Wt = (const float*)d_in[2];
  const float* bt = (const float*)d_in[3];
  const float* Wq = (const float*)d_in[4];
  const float* Wk = (const float*)d_in[5];
  const float* Wv = (const float*)d_in[6];
  const float* Wp = (const float*)d_in[7];
  const float* bp = (const float*)d_in[8];
  char* ws = (char*)d_ws;
  float* temb        = (float*)ws;                              // 32 KB
  unsigned short* wb = (unsigned short*)(ws + 32768);           // 512 KB (q,k,v,p)
  unsigned short* xb = (unsigned short*)(ws + 557056);          // 16 MB [n,s,c]
  unsigned short* qb = (unsigned short*)(ws + 17334272);        // 16 MB [n,s,d]
  unsigned short* kb = (unsigned short*)(ws + 34111488);        // 16 MB [n,s,d]
  unsigned short* vtb = (unsigned short*)(ws + 50888704);       // 16 MB [n,d,s]
  unsigned short* ob = (unsigned short*)(ws + 67665920);        // 16 MB [n,s,d]
  float* out = (float*)d_out;

  k_misc<<<1056, 256, 0, stream>>>(t, Wt, bt, temb, Wq, Wk, Wv, Wp, wb);
  k_addT<<<dim3(8, 32, 32), 256, 0, stream>>>(x, temb, xb);
  k_qkv<<<dim3(8, 2, 96), 256, 0, stream>>>(xb, wb, qb, kb, vtb);
  k_attn<<<512, 256, 0, stream>>>(qb, kb, vtb, ob);
  k_proj<<<dim3(8, 2, 32), 256, 0, stream>>>(ob, wb + 196608, bp, x, out);
}

// Round 10
// 144.454 us; speedup vs baseline: 1.3117x; 1.3117x over previous
//
#include <hip/hip_runtime.h>
#include <hip/hip_bf16.h>

#define NB 32
#define CD 256
#define SS 1024
#define DD 256
#define TT 512
// SCALE * log2(e): softmax computed in base-2
#define QSCALE 0.09016844f

typedef __attribute__((ext_vector_type(8))) short s16x8;
typedef __attribute__((ext_vector_type(4))) short s16x4;
typedef __attribute__((ext_vector_type(4))) float f32x4;
typedef __attribute__((ext_vector_type(16))) float f32x16;
typedef __attribute__((ext_vector_type(4))) unsigned int u32x4;

__device__ __forceinline__ unsigned short f2bf(float f) {
  unsigned u = __builtin_bit_cast(unsigned, f);
  u = (u + 0x7FFFu + ((u >> 16) & 1u)) >> 16;
  return (unsigned short)u;
}
__device__ __forceinline__ float bf2f(unsigned short h) {
  return __builtin_bit_cast(float, ((unsigned)h) << 16);
}
__device__ __forceinline__ unsigned pk2(float a, float b) {
  float2 f2; f2.x = a; f2.y = b;
  __hip_bfloat162 h = __float22bfloat162_rn(f2);
  unsigned u;
  __builtin_memcpy(&u, &h, 4);
  return u;
}
__device__ __forceinline__ float asf(unsigned u) {
  return __builtin_bit_cast(float, u);
}
#define GLOAD16(gp, lp)                                                        \
  __builtin_amdgcn_global_load_lds(                                            \
      (const __attribute__((address_space(1))) unsigned int*)(const void*)(gp),\
      (__attribute__((address_space(3))) unsigned int*)(void*)(lp), 16, 0, 0)

// ---- misc: blocks 0..1023 = weight fp32->bf16; 1024..1055 = temb ----
__global__ __launch_bounds__(256) void k_misc(const float* __restrict__ t,
    const float* __restrict__ Wt, const float* __restrict__ bt, float* __restrict__ temb,
    const float* __restrict__ wq, const float* __restrict__ wk,
    const float* __restrict__ wv, const float* __restrict__ wp,
    unsigned short* __restrict__ dst) {
  const int b = blockIdx.x;
  if (b < 1024) {
    const int i = b * 256 + threadIdx.x;
    const int which = i >> 16, off = i & 65535;
    const float* s = which == 0 ? wq : which == 1 ? wk : which == 2 ? wv : wp;
    dst[i] = f2bf(s[off]);
  } else {
    const int n = b - 1024, c = threadIdx.x;
    const float4* tv = (const float4*)(t + (size_t)n * TT);
    const float4* wvv = (const float4*)(Wt + (size_t)c * TT);
    float acc = 0.f;
#pragma unroll 8
    for (int i = 0; i < TT / 4; ++i) {
      float4 a = tv[i], bb = wvv[i];
      acc += a.x * bb.x + a.y * bb.y + a.z * bb.z + a.w * bb.w;
    }
    acc += bt[c];
    temb[n * CD + c] = fmaxf(acc, 0.f);
  }
}

// ---- xb[n, s, c] = bf16(x[n,c,s] + temb[n,c]) ----
__global__ __launch_bounds__(256) void k_addT(const float* __restrict__ x,
    const float* __restrict__ temb, unsigned short* __restrict__ xb) {
  __shared__ float tile[32][33];
  const int tx = threadIdx.x & 31, ty = threadIdx.x >> 5;
  const int n = blockIdx.z, s0 = blockIdx.y * 32, c0 = blockIdx.x * 32;
#pragma unroll
  for (int i = 0; i < 4; ++i) {
    const int cc = ty + i * 8;
    tile[cc][tx] = x[((size_t)n * CD + c0 + cc) * SS + s0 + tx] + temb[n * CD + c0 + cc];
  }
  __syncthreads();
  unsigned short* op = xb + ((size_t)n * SS + s0) * CD + c0;
#pragma unroll
  for (int i = 0; i < 4; ++i) {
    const int ss = ty + i * 8;
    op[(size_t)ss * CD + tx] = f2bf(tile[tx][ss]);
  }
}

// ---- QKV GEMM: z = which*32 + n. which==2 writes V transposed. ----
__global__ __launch_bounds__(256) void k_qkv(const unsigned short* __restrict__ A,
    const unsigned short* __restrict__ wb, unsigned short* __restrict__ qb,
    unsigned short* __restrict__ kb, unsigned short* __restrict__ vtb) {
  __shared__ __attribute__((aligned(16))) unsigned short As[128 * 32];
  __shared__ __attribute__((aligned(16))) unsigned short Bs[128 * 32];
  const int which = blockIdx.z >> 5, n = blockIdx.z & 31;
  const int s0 = blockIdx.x * 128;
  const int d0 = blockIdx.y * 128;
  const unsigned short* B = wb + which * 65536;
  const int tid = threadIdx.x;
  const int lane = tid & 63, wid = tid >> 6;
  const int lo = lane & 15, hi = lane >> 4;
  const int wr = wid >> 1, wc = wid & 1;
  const unsigned short* An = A + (size_t)n * SS * CD;
  f32x4 acc[4][4] = {};
  for (int k0 = 0; k0 < CD; k0 += 32) {
#pragma unroll
    for (int i = 0; i < 2; ++i) {
      const int seg = i * 256 + wid * 64 + lane;
      const int row = seg >> 2, c8 = seg & 3;
      GLOAD16(An + (size_t)(s0 + row) * CD + k0 + c8 * 8, As + (size_t)(i * 256 + wid * 64) * 8);
      GLOAD16(B + (size_t)(d0 + row) * CD + k0 + c8 * 8, Bs + (size_t)(i * 256 + wid * 64) * 8);
    }
    __syncthreads();
    s16x8 a[4], b[4];
#pragma unroll
    for (int mi = 0; mi < 4; ++mi)
      a[mi] = *(const s16x8*)&As[(wr * 64 + mi * 16 + lo) * 32 + hi * 8];
#pragma unroll
    for (int ni = 0; ni < 4; ++ni)
      b[ni] = *(const s16x8*)&Bs[(wc * 64 + ni * 16 + lo) * 32 + hi * 8];
#pragma unroll
    for (int mi = 0; mi < 4; ++mi)
#pragma unroll
      for (int ni = 0; ni < 4; ++ni)
        acc[mi][ni] = __builtin_amdgcn_mfma_f32_16x16x32_bf16(a[mi], b[ni], acc[mi][ni], 0, 0, 0);
    __syncthreads();
  }
  if (which < 2) {
    const float osc = which == 0 ? QSCALE : 1.0f;
    unsigned short* On = (which == 0 ? qb : kb) + (size_t)n * SS * DD;
#pragma unroll
    for (int mi = 0; mi < 4; ++mi) {
      const int r0 = s0 + wr * 64 + mi * 16 + hi * 4;
#pragma unroll
      for (int ni = 0; ni < 4; ++ni) {
        const int col = d0 + wc * 64 + ni * 16 + lo;
#pragma unroll
        for (int r = 0; r < 4; ++r)
          On[(size_t)(r0 + r) * DD + col] = f2bf(acc[mi][ni][r] * osc);
      }
    }
  } else {
    unsigned short* On = vtb + (size_t)n * DD * SS;
#pragma unroll
    for (int mi = 0; mi < 4; ++mi) {
      const int r0 = s0 + wr * 64 + mi * 16 + hi * 4;
#pragma unroll
      for (int ni = 0; ni < 4; ++ni) {
        const int col = d0 + wc * 64 + ni * 16 + lo;
        s16x4 v;
#pragma unroll
        for (int r = 0; r < 4; ++r) v[r] = (short)f2bf(acc[mi][ni][r]);
        *(s16x4*)&On[(size_t)col * SS + r0] = v;
      }
    }
  }
}

// ---- flash attention, swapped 32x32 MFMA, fully in-register softmax+P
// (permlane32_swap builtin). grid 512 with n->XCD swizzle (xcd=bid&7).
// 4 waves x 32 q-rows; lane owns q=lane&31. K/V^T dbuf in LDS (KVBLK=32,
// XOR-swizzled). QK^T uses TWO independent MFMA chains (even/odd k) to halve
// dependent-latency. 48KB LDS; launch_bounds(256,2) = spill-free regime. ----
__global__ __launch_bounds__(256, 2) void k_attn(const unsigned short* __restrict__ qb,
    const unsigned short* __restrict__ kb, const unsigned short* __restrict__ vtb,
    unsigned short* __restrict__ ob) {
  // ushort elems: Ks[2][8192] @0, Vs[2][4096] @16384  => 48KB
  __shared__ __attribute__((aligned(16))) unsigned short lds[24576];
  const int bid = blockIdx.x;
  const int xcd = bid & 7, inner = bid >> 3;
  const int n = xcd + ((inner >> 4) << 3);
  const int sub = inner & 15;
  const int qt = sub & 7, dh = sub >> 3;
  const int tid = threadIdx.x, lane = tid & 63, w = tid >> 6;
  const int l31 = lane & 31, h = lane >> 5;
  const int dblk = dh * 128;
  const unsigned short* Kn = kb + (size_t)n * SS * DD;
  const unsigned short* Vn = vtb + ((size_t)n * DD + dblk) * SS;
  const int qrow = qt * 128 + w * 32 + l31;

  const unsigned short* Qp = qb + ((size_t)n * SS + qrow) * DD + h * 8;
  s16x8 qf[16];
#pragma unroll
  for (int ks = 0; ks < 16; ++ks) qf[ks] = *(const s16x8*)(Qp + ks * 16);

  f32x16 acc[4] = {};
  float mrun = -3.0e38f, lrun = 0.f;

  auto STAGE = [&](int buf, int jt) {
    const int j0 = jt * 32;
    unsigned short* KsB = lds + buf * 8192;
    unsigned short* VsB = lds + 16384 + buf * 4096;
#pragma unroll
    for (int i = 0; i < 4; ++i) {  // K: 32 rows x 256 cols
      const int idx = i * 256 + w * 64 + lane;
      const int row = idx >> 5, c8 = idx & 31;
      GLOAD16(Kn + (size_t)(j0 + row) * DD + ((c8 ^ (row & 7)) << 3),
              KsB + (size_t)(i * 256 + w * 64) * 8);
    }
#pragma unroll
    for (int i = 0; i < 2; ++i) {  // V^T: 128 d-rows x 32 j-cols
      const int idx = i * 256 + w * 64 + lane;
      const int row = idx >> 2, c8 = idx & 3;
      GLOAD16(Vn + (size_t)row * SS + j0 + ((c8 ^ ((row >> 1) & 3)) << 3),
              VsB + (size_t)(i * 256 + w * 64) * 8);
    }
  };

  STAGE(0, 0);
  __syncthreads();

  int cur = 0;
#pragma unroll 1
  for (int jt = 0; jt < 32; ++jt) {
    if (jt + 1 < 32) STAGE(cur ^ 1, jt + 1);
    const unsigned short* Ks = lds + cur * 8192;
    const unsigned short* Vs = lds + 16384 + cur * 4096;
    // ---- QK^T (swapped), 2 independent chains: lane holds S[j=crow(r,h)][q=l31]
    f32x16 sca = {}, scb = {};
    __builtin_amdgcn_s_setprio(1);
#pragma unroll
    for (int ks = 0; ks < 16; ks += 2) {
      const s16x8 kfa = *(const s16x8*)&Ks[l31 * 256 + ((((ks * 2 + h)) ^ (l31 & 7)) << 3)];
      const s16x8 kfb = *(const s16x8*)&Ks[l31 * 256 + (((((ks + 1) * 2 + h)) ^ (l31 & 7)) << 3)];
      sca = __builtin_amdgcn_mfma_f32_32x32x16_bf16(kfa, qf[ks], sca, 0, 0, 0);
      scb = __builtin_amdgcn_mfma_f32_32x32x16_bf16(kfb, qf[ks + 1], scb, 0, 0, 0);
    }
    __builtin_amdgcn_s_setprio(0);
    f32x16 sc = sca + scb;
    // ---- online softmax in base-2; pair {lane, lane^32} via permlane swap ----
    float pm = fmaxf(fmaxf(fmaxf(sc[0], sc[1]), fmaxf(sc[2], sc[3])),
                     fmaxf(fmaxf(sc[4], sc[5]), fmaxf(sc[6], sc[7])));
    pm = fmaxf(pm, fmaxf(fmaxf(fmaxf(sc[8], sc[9]), fmaxf(sc[10], sc[11])),
                         fmaxf(fmaxf(sc[12], sc[13]), fmaxf(sc[14], sc[15]))));
    {
      auto rp = __builtin_amdgcn_permlane32_swap(__builtin_bit_cast(unsigned, pm),
                                                 __builtin_bit_cast(unsigned, pm), false, false);
      pm = fmaxf(asf(rp[0]), asf(rp[1]));
    }
    if (__any(pm > mrun + 8.f)) {
      const float mn = fmaxf(mrun, pm);
      const float corr = exp2f(mrun - mn);
      mrun = mn; lrun *= corr;
#pragma unroll
      for (int dc = 0; dc < 4; ++dc)
#pragma unroll
        for (int i = 0; i < 16; ++i) acc[dc][i] *= corr;
    }
#pragma unroll
    for (int i = 0; i < 16; ++i) sc[i] = exp2f(sc[i] - mrun);
    lrun += (((sc[0] + sc[1]) + (sc[2] + sc[3])) + ((sc[4] + sc[5]) + (sc[6] + sc[7]))) +
            (((sc[8] + sc[9]) + (sc[10] + sc[11])) + ((sc[12] + sc[13]) + (sc[14] + sc[15])));
    // ---- P -> A-fragments fully in-register.
    // wv0=j{0,1}/{4,5}, wv1=j{2,3}/{6,7}, wv2=j{8,9}/{12,13}, wv3=j{10,11}/{14,15}
    // swap(a,b): a.hi<->b.lo => word0=swap(wv0,wv2)[0], word2=[1]; word1/3 from (wv1,wv3).
    const unsigned wv0 = pk2(sc[0], sc[1]),   wv1 = pk2(sc[2], sc[3]);
    const unsigned wv2 = pk2(sc[4], sc[5]),   wv3 = pk2(sc[6], sc[7]);
    const unsigned wv4 = pk2(sc[8], sc[9]),   wv5 = pk2(sc[10], sc[11]);
    const unsigned wv6 = pk2(sc[12], sc[13]), wv7 = pk2(sc[14], sc[15]);
    auto r02 = __builtin_amdgcn_permlane32_swap(wv0, wv2, false, false);
    auto r13 = __builtin_amdgcn_permlane32_swap(wv1, wv3, false, false);
    auto r46 = __builtin_amdgcn_permlane32_swap(wv4, wv6, false, false);
    auto r57 = __builtin_amdgcn_permlane32_swap(wv5, wv7, false, false);
    const u32x4 pa0u = {r02[0], r13[0], r02[1], r13[1]};
    const u32x4 pa1u = {r46[0], r57[0], r46[1], r57[1]};
    const s16x8 pa0 = __builtin_bit_cast(s16x8, pa0u);
    const s16x8 pa1 = __builtin_bit_cast(s16x8, pa1u);
    // ---- PV from Vs[cur] ----
    __builtin_amdgcn_s_setprio(1);
#pragma unroll
    for (int dc = 0; dc < 4; ++dc) {
      const s16x8 vf0 = *(const s16x8*)&Vs[(dc * 32 + l31) * 32 + ((h ^ ((l31 >> 1) & 3)) << 3)];
      acc[dc] = __builtin_amdgcn_mfma_f32_32x32x16_bf16(vf0, pa0, acc[dc], 0, 0, 0);
    }
#pragma unroll
    for (int dc = 0; dc < 4; ++dc) {
      const s16x8 vf1 = *(const s16x8*)&Vs[(dc * 32 + l31) * 32 + (((2 + h) ^ ((l31 >> 1) & 3)) << 3)];
      acc[dc] = __builtin_amdgcn_mfma_f32_32x32x16_bf16(vf1, pa1, acc[dc], 0, 0, 0);
    }
    __builtin_amdgcn_s_setprio(0);
    __syncthreads();  // drains vmcnt(0): next tile staged; waves past cur
    cur ^= 1;
  }
  {
    auto rl = __builtin_amdgcn_permlane32_swap(__builtin_bit_cast(unsigned, lrun),
                                               __builtin_bit_cast(unsigned, lrun), false, false);
    lrun = asf(rl[0]) + asf(rl[1]);
  }
  const float inv = 1.0f / lrun;
  unsigned short* Op = ob + ((size_t)n * SS + qrow) * DD + dblk;
#pragma unroll
  for (int dc = 0; dc < 4; ++dc)
#pragma unroll
    for (int rg = 0; rg < 4; ++rg) {
      uint2 u;
      u.x = pk2(acc[dc][rg * 4 + 0] * inv, acc[dc][rg * 4 + 1] * inv);
      u.y = pk2(acc[dc][rg * 4 + 2] * inv, acc[dc][rg * 4 + 3] * inv);
      *(uint2*)(Op + dc * 32 + rg * 8 + h * 4) = u;
    }
}

// ---- fused proj + bias + residual ----
__global__ __launch_bounds__(256) void k_proj(const unsigned short* __restrict__ ob,
    const unsigned short* __restrict__ wpb, const float* __restrict__ bp,
    const float* __restrict__ x, float* __restrict__ out) {
  __shared__ __attribute__((aligned(16))) unsigned short As[128 * 32];
  __shared__ __attribute__((aligned(16))) unsigned short Bs[128 * 32];
  const int n = blockIdx.z;
  const int s0 = blockIdx.x * 128;
  const int c0 = blockIdx.y * 128;
  const int tid = threadIdx.x;
  const int lane = tid & 63, wid = tid >> 6;
  const int lo = lane & 15, hi = lane >> 4;
  const int wr = wid >> 1, wc = wid & 1;
  const unsigned short* On = ob + (size_t)n * SS * DD;
  f32x4 acc[4][4] = {};
  for (int k0 = 0; k0 < DD; k0 += 32) {
#pragma unroll
    for (int i = 0; i < 2; ++i) {
      const int seg = i * 256 + wid * 64 + lane;
      const int row = seg >> 2, c8 = seg & 3;
      GLOAD16(wpb + (size_t)(c0 + row) * DD + k0 + c8 * 8, As + (size_t)(i * 256 + wid * 64) * 8);
      GLOAD16(On + (size_t)(s0 + row) * DD + k0 + c8 * 8, Bs + (size_t)(i * 256 + wid * 64) * 8);
    }
    __syncthreads();
    s16x8 a[4], b[4];
#pragma unroll
    for (int mi = 0; mi < 4; ++mi)
      a[mi] = *(const s16x8*)&As[(wr * 64 + mi * 16 + lo) * 32 + hi * 8];
#pragma unroll
    for (int ni = 0; ni < 4; ++ni)
      b[ni] = *(const s16x8*)&Bs[(wc * 64 + ni * 16 + lo) * 32 + hi * 8];
#pragma unroll
    for (int mi = 0; mi < 4; ++mi)
#pragma unroll
      for (int ni = 0; ni < 4; ++ni)
        acc[mi][ni] = __builtin_amdgcn_mfma_f32_16x16x32_bf16(a[mi], b[ni], acc[mi][ni], 0, 0, 0);
    __syncthreads();
  }
#pragma unroll
  for (int mi = 0; mi < 4; ++mi) {
#pragma unroll
    for (int r = 0; r < 4; ++r) {
      const int c = c0 + wr * 64 + mi * 16 + hi * 4 + r;
      const float bpc = bp[c];
      const size_t base = ((size_t)n * CD + c) * SS;
#pragma unroll
      for (int ni = 0; ni < 4; ++ni) {
        const int s = s0 + wc * 64 + ni * 16 + lo;
        out[base + s] = acc[mi][ni][r] + bpc + x[base + s];
      }
    }
  }
}

extern "C" void kernel_launch(void* const* d_in, const int* in_sizes, int n_in,
                              void* d_out, int out_size, void* d_ws, size_t ws_size,
                              hipStream_t stream) {
  const float* x  = (const float*)d_in[0];
  const float* t  = (const float*)d_in[1];
  const float* Wt = (const float*)d_in[2];
  const float* bt = (const float*)d_in[3];
  const float* Wq = (const float*)d_in[4];
  const float* Wk = (const float*)d_in[5];
  const float* Wv = (const float*)d_in[6];
  const float* Wp = (const float*)d_in[7];
  const float* bp = (const float*)d_in[8];
  char* ws = (char*)d_ws;
  float* temb        = (float*)ws;                              // 32 KB
  unsigned short* wb = (unsigned short*)(ws + 32768);           // 512 KB (q,k,v,p)
  unsigned short* xb = (unsigned short*)(ws + 557056);          // 16 MB [n,s,c]
  unsigned short* qb = (unsigned short*)(ws + 17334272);        // 16 MB [n,s,d]
  unsigned short* kb = (unsigned short*)(ws + 34111488);        // 16 MB [n,s,d]
  unsigned short* vtb = (unsigned short*)(ws + 50888704);       // 16 MB [n,d,s]
  unsigned short* ob = (unsigned short*)(ws + 67665920);        // 16 MB [n,s,d]
  float* out = (float*)d_out;

  k_misc<<<1056, 256, 0, stream>>>(t, Wt, bt, temb, Wq, Wk, Wv, Wp, wb);
  k_addT<<<dim3(8, 32, 32), 256, 0, stream>>>(x, temb, xb);
  k_qkv<<<dim3(8, 2, 96), 256, 0, stream>>>(xb, wb, qb, kb, vtb);
  k_attn<<<512, 256, 0, stream>>>(qb, kb, vtb, ob);
  k_proj<<<dim3(8, 2, 32), 256, 0, stream>>>(ob, wb + 196608, bp, x, out);
}

// Round 11
// 142.070 us; speedup vs baseline: 1.3337x; 1.0168x over previous
//
#include <hip/hip_runtime.h>
#include <hip/hip_bf16.h>

#define NB 32
#define CD 256
#define SS 1024
#define DD 256
#define TT 512
// SCALE * log2(e): softmax computed in base-2
#define QSCALE 0.09016844f

typedef __attribute__((ext_vector_type(8))) short s16x8;
typedef __attribute__((ext_vector_type(4))) short s16x4;
typedef __attribute__((ext_vector_type(4))) float f32x4;
typedef __attribute__((ext_vector_type(16))) float f32x16;
typedef __attribute__((ext_vector_type(4))) unsigned int u32x4;

__device__ __forceinline__ unsigned short f2bf(float f) {
  unsigned u = __builtin_bit_cast(unsigned, f);
  u = (u + 0x7FFFu + ((u >> 16) & 1u)) >> 16;
  return (unsigned short)u;
}
__device__ __forceinline__ float bf2f(unsigned short h) {
  return __builtin_bit_cast(float, ((unsigned)h) << 16);
}
__device__ __forceinline__ unsigned pk2(float a, float b) {
  float2 f2; f2.x = a; f2.y = b;
  __hip_bfloat162 h = __float22bfloat162_rn(f2);
  unsigned u;
  __builtin_memcpy(&u, &h, 4);
  return u;
}
__device__ __forceinline__ float asf(unsigned u) {
  return __builtin_bit_cast(float, u);
}
#define GLOAD16(gp, lp)                                                        \
  __builtin_amdgcn_global_load_lds(                                            \
      (const __attribute__((address_space(1))) unsigned int*)(const void*)(gp),\
      (__attribute__((address_space(3))) unsigned int*)(void*)(lp), 16, 0, 0)

// ---- misc: blocks 0..1023 = weight fp32->bf16; 1024..1055 = temb ----
__global__ __launch_bounds__(256) void k_misc(const float* __restrict__ t,
    const float* __restrict__ Wt, const float* __restrict__ bt, float* __restrict__ temb,
    const float* __restrict__ wq, const float* __restrict__ wk,
    const float* __restrict__ wv, const float* __restrict__ wp,
    unsigned short* __restrict__ dst) {
  const int b = blockIdx.x;
  if (b < 1024) {
    const int i = b * 256 + threadIdx.x;
    const int which = i >> 16, off = i & 65535;
    const float* s = which == 0 ? wq : which == 1 ? wk : which == 2 ? wv : wp;
    dst[i] = f2bf(s[off]);
  } else {
    const int n = b - 1024, c = threadIdx.x;
    const float4* tv = (const float4*)(t + (size_t)n * TT);
    const float4* wvv = (const float4*)(Wt + (size_t)c * TT);
    float acc = 0.f;
#pragma unroll 8
    for (int i = 0; i < TT / 4; ++i) {
      float4 a = tv[i], bb = wvv[i];
      acc += a.x * bb.x + a.y * bb.y + a.z * bb.z + a.w * bb.w;
    }
    acc += bt[c];
    temb[n * CD + c] = fmaxf(acc, 0.f);
  }
}

// ---- xb[n, s, c] = bf16(x[n,c,s] + temb[n,c]) ----
__global__ __launch_bounds__(256) void k_addT(const float* __restrict__ x,
    const float* __restrict__ temb, unsigned short* __restrict__ xb) {
  __shared__ float tile[32][33];
  const int tx = threadIdx.x & 31, ty = threadIdx.x >> 5;
  const int n = blockIdx.z, s0 = blockIdx.y * 32, c0 = blockIdx.x * 32;
#pragma unroll
  for (int i = 0; i < 4; ++i) {
    const int cc = ty + i * 8;
    tile[cc][tx] = x[((size_t)n * CD + c0 + cc) * SS + s0 + tx] + temb[n * CD + c0 + cc];
  }
  __syncthreads();
  unsigned short* op = xb + ((size_t)n * SS + s0) * CD + c0;
#pragma unroll
  for (int i = 0; i < 4; ++i) {
    const int ss = ty + i * 8;
    op[(size_t)ss * CD + tx] = f2bf(tile[tx][ss]);
  }
}

// ---- QKV GEMM: z = which*32 + n. which==2 writes V transposed. ----
__global__ __launch_bounds__(256) void k_qkv(const unsigned short* __restrict__ A,
    const unsigned short* __restrict__ wb, unsigned short* __restrict__ qb,
    unsigned short* __restrict__ kb, unsigned short* __restrict__ vtb) {
  __shared__ __attribute__((aligned(16))) unsigned short As[128 * 32];
  __shared__ __attribute__((aligned(16))) unsigned short Bs[128 * 32];
  const int which = blockIdx.z >> 5, n = blockIdx.z & 31;
  const int s0 = blockIdx.x * 128;
  const int d0 = blockIdx.y * 128;
  const unsigned short* B = wb + which * 65536;
  const int tid = threadIdx.x;
  const int lane = tid & 63, wid = tid >> 6;
  const int lo = lane & 15, hi = lane >> 4;
  const int wr = wid >> 1, wc = wid & 1;
  const unsigned short* An = A + (size_t)n * SS * CD;
  f32x4 acc[4][4] = {};
  for (int k0 = 0; k0 < CD; k0 += 32) {
#pragma unroll
    for (int i = 0; i < 2; ++i) {
      const int seg = i * 256 + wid * 64 + lane;
      const int row = seg >> 2, c8 = seg & 3;
      GLOAD16(An + (size_t)(s0 + row) * CD + k0 + c8 * 8, As + (size_t)(i * 256 + wid * 64) * 8);
      GLOAD16(B + (size_t)(d0 + row) * CD + k0 + c8 * 8, Bs + (size_t)(i * 256 + wid * 64) * 8);
    }
    __syncthreads();
    s16x8 a[4], b[4];
#pragma unroll
    for (int mi = 0; mi < 4; ++mi)
      a[mi] = *(const s16x8*)&As[(wr * 64 + mi * 16 + lo) * 32 + hi * 8];
#pragma unroll
    for (int ni = 0; ni < 4; ++ni)
      b[ni] = *(const s16x8*)&Bs[(wc * 64 + ni * 16 + lo) * 32 + hi * 8];
#pragma unroll
    for (int mi = 0; mi < 4; ++mi)
#pragma unroll
      for (int ni = 0; ni < 4; ++ni)
        acc[mi][ni] = __builtin_amdgcn_mfma_f32_16x16x32_bf16(a[mi], b[ni], acc[mi][ni], 0, 0, 0);
    __syncthreads();
  }
  if (which < 2) {
    const float osc = which == 0 ? QSCALE : 1.0f;
    unsigned short* On = (which == 0 ? qb : kb) + (size_t)n * SS * DD;
#pragma unroll
    for (int mi = 0; mi < 4; ++mi) {
      const int r0 = s0 + wr * 64 + mi * 16 + hi * 4;
#pragma unroll
      for (int ni = 0; ni < 4; ++ni) {
        const int col = d0 + wc * 64 + ni * 16 + lo;
#pragma unroll
        for (int r = 0; r < 4; ++r)
          On[(size_t)(r0 + r) * DD + col] = f2bf(acc[mi][ni][r] * osc);
      }
    }
  } else {
    unsigned short* On = vtb + (size_t)n * DD * SS;
#pragma unroll
    for (int mi = 0; mi < 4; ++mi) {
      const int r0 = s0 + wr * 64 + mi * 16 + hi * 4;
#pragma unroll
      for (int ni = 0; ni < 4; ++ni) {
        const int col = d0 + wc * 64 + ni * 16 + lo;
        s16x4 v;
#pragma unroll
        for (int r = 0; r < 4; ++r) v[r] = (short)f2bf(acc[mi][ni][r]);
        *(s16x4*)&On[(size_t)col * SS + r0] = v;
      }
    }
  }
}

// ---- flash attention, swapped 32x32 MFMA, in-register softmax+P (permlane).
// 8-wave blocks (512 thr), KVBLK=64 as two 32-j sub-tiles per barrier.
// grid 256: xcd=bid&7, n=xcd+8*(idx>>3); 8 blocks per n (4 qt x 2 dh) share
// one XCD's L2. wave = 32 q-rows; lane owns q=lane&31. K/V^T dbuf in LDS
// (96KB), XOR-swizzled, linear dest + pre-swizzled source. ----
__global__ __launch_bounds__(512, 2) void k_attn(const unsigned short* __restrict__ qb,
    const unsigned short* __restrict__ kb, const unsigned short* __restrict__ vtb,
    unsigned short* __restrict__ ob) {
  // ushort elems: Ks[2][64*256] @0, Vs[2][128*64] @32768  => 96KB
  __shared__ __attribute__((aligned(16))) unsigned short lds[49152];
  const int bid = blockIdx.x;
  const int xcd = bid & 7, idx = bid >> 3;
  const int n = xcd + ((idx >> 3) << 3);
  const int sub = idx & 7;
  const int qt = sub & 3, dh = sub >> 2;
  const int tid = threadIdx.x, lane = tid & 63, w = tid >> 6;
  const int l31 = lane & 31, h = lane >> 5;
  const int dblk = dh * 128;
  const unsigned short* Kn = kb + (size_t)n * SS * DD;
  const unsigned short* Vn = vtb + ((size_t)n * DD + dblk) * SS;
  const int qrow = qt * 256 + w * 32 + l31;

  const unsigned short* Qp = qb + ((size_t)n * SS + qrow) * DD + h * 8;
  s16x8 qf[16];
#pragma unroll
  for (int ks = 0; ks < 16; ++ks) qf[ks] = *(const s16x8*)(Qp + ks * 16);

  f32x16 acc[4] = {};
  float mrun = -3.0e38f, lrun = 0.f;

  auto STAGE = [&](int buf, int jt) {
    const int j0 = jt * 64;
    unsigned short* KsB = lds + buf * 16384;
    unsigned short* VsB = lds + 32768 + buf * 8192;
#pragma unroll
    for (int i = 0; i < 4; ++i) {  // K: 64 rows x 256 cols (32KB)
      const int gidx = i * 512 + tid;
      const int row = gidx >> 5, c8 = gidx & 31;
      GLOAD16(Kn + (size_t)(j0 + row) * DD + ((c8 ^ (row & 7)) << 3),
              KsB + (size_t)(i * 512 + w * 64) * 8);
    }
#pragma unroll
    for (int i = 0; i < 2; ++i) {  // V^T: 128 d-rows x 64 j-cols (16KB)
      const int gidx = i * 512 + tid;
      const int row = gidx >> 3, c8 = gidx & 7;
      GLOAD16(Vn + (size_t)row * SS + j0 + ((c8 ^ (row & 7)) << 3),
              VsB + (size_t)(i * 512 + w * 64) * 8);
    }
  };

  STAGE(0, 0);
  __syncthreads();

  int cur = 0;
#pragma unroll 1
  for (int jt = 0; jt < 16; ++jt) {
    if (jt + 1 < 16) STAGE(cur ^ 1, jt + 1);
    const unsigned short* Ks = lds + cur * 16384;
    const unsigned short* Vs = lds + 32768 + cur * 8192;
    // ---- QK^T, two independent 32-j sub-tiles (rows 0..31 and 32..63) ----
    f32x16 scA = {}, scB = {};
    __builtin_amdgcn_s_setprio(1);
#pragma unroll
    for (int ks = 0; ks < 16; ++ks) {
      const s16x8 kfA = *(const s16x8*)&Ks[l31 * 256 + (((ks * 2 + h) ^ (l31 & 7)) << 3)];
      const s16x8 kfB = *(const s16x8*)&Ks[(32 + l31) * 256 + (((ks * 2 + h) ^ (l31 & 7)) << 3)];
      scA = __builtin_amdgcn_mfma_f32_32x32x16_bf16(kfA, qf[ks], scA, 0, 0, 0);
      scB = __builtin_amdgcn_mfma_f32_32x32x16_bf16(kfB, qf[ks], scB, 0, 0, 0);
    }
    __builtin_amdgcn_s_setprio(0);
    // ================= sub-tile A: softmax + PV =================
    {
      float pm = fmaxf(fmaxf(fmaxf(scA[0], scA[1]), fmaxf(scA[2], scA[3])),
                       fmaxf(fmaxf(scA[4], scA[5]), fmaxf(scA[6], scA[7])));
      pm = fmaxf(pm, fmaxf(fmaxf(fmaxf(scA[8], scA[9]), fmaxf(scA[10], scA[11])),
                           fmaxf(fmaxf(scA[12], scA[13]), fmaxf(scA[14], scA[15]))));
      auto rp = __builtin_amdgcn_permlane32_swap(__builtin_bit_cast(unsigned, pm),
                                                 __builtin_bit_cast(unsigned, pm), false, false);
      pm = fmaxf(asf(rp[0]), asf(rp[1]));
      if (__any(pm > mrun + 8.f)) {
        const float mn = fmaxf(mrun, pm);
        const float corr = exp2f(mrun - mn);
        mrun = mn; lrun *= corr;
#pragma unroll
        for (int dc = 0; dc < 4; ++dc)
#pragma unroll
          for (int i = 0; i < 16; ++i) acc[dc][i] *= corr;
      }
#pragma unroll
      for (int i = 0; i < 16; ++i) scA[i] = exp2f(scA[i] - mrun);
      lrun += (((scA[0] + scA[1]) + (scA[2] + scA[3])) + ((scA[4] + scA[5]) + (scA[6] + scA[7]))) +
              (((scA[8] + scA[9]) + (scA[10] + scA[11])) + ((scA[12] + scA[13]) + (scA[14] + scA[15])));
      const unsigned wv0 = pk2(scA[0], scA[1]),   wv1 = pk2(scA[2], scA[3]);
      const unsigned wv2 = pk2(scA[4], scA[5]),   wv3 = pk2(scA[6], scA[7]);
      const unsigned wv4 = pk2(scA[8], scA[9]),   wv5 = pk2(scA[10], scA[11]);
      const unsigned wv6 = pk2(scA[12], scA[13]), wv7 = pk2(scA[14], scA[15]);
      auto r02 = __builtin_amdgcn_permlane32_swap(wv0, wv2, false, false);
      auto r13 = __builtin_amdgcn_permlane32_swap(wv1, wv3, false, false);
      auto r46 = __builtin_amdgcn_permlane32_swap(wv4, wv6, false, false);
      auto r57 = __builtin_amdgcn_permlane32_swap(wv5, wv7, false, false);
      const u32x4 pa0u = {r02[0], r13[0], r02[1], r13[1]};
      const u32x4 pa1u = {r46[0], r57[0], r46[1], r57[1]};
      const s16x8 pa0 = __builtin_bit_cast(s16x8, pa0u);
      const s16x8 pa1 = __builtin_bit_cast(s16x8, pa1u);
      __builtin_amdgcn_s_setprio(1);
#pragma unroll
      for (int dc = 0; dc < 4; ++dc) {
        const s16x8 vf = *(const s16x8*)&Vs[(dc * 32 + l31) * 64 + ((h ^ (l31 & 7)) << 3)];
        acc[dc] = __builtin_amdgcn_mfma_f32_32x32x16_bf16(vf, pa0, acc[dc], 0, 0, 0);
      }
#pragma unroll
      for (int dc = 0; dc < 4; ++dc) {
        const s16x8 vf = *(const s16x8*)&Vs[(dc * 32 + l31) * 64 + (((2 + h) ^ (l31 & 7)) << 3)];
        acc[dc] = __builtin_amdgcn_mfma_f32_32x32x16_bf16(vf, pa1, acc[dc], 0, 0, 0);
      }
      __builtin_amdgcn_s_setprio(0);
    }
    // ================= sub-tile B: softmax + PV =================
    {
      float pm = fmaxf(fmaxf(fmaxf(scB[0], scB[1]), fmaxf(scB[2], scB[3])),
                       fmaxf(fmaxf(scB[4], scB[5]), fmaxf(scB[6], scB[7])));
      pm = fmaxf(pm, fmaxf(fmaxf(fmaxf(scB[8], scB[9]), fmaxf(scB[10], scB[11])),
                           fmaxf(fmaxf(scB[12], scB[13]), fmaxf(scB[14], scB[15]))));
      auto rp = __builtin_amdgcn_permlane32_swap(__builtin_bit_cast(unsigned, pm),
                                                 __builtin_bit_cast(unsigned, pm), false, false);
      pm = fmaxf(asf(rp[0]), asf(rp[1]));
      if (__any(pm > mrun + 8.f)) {
        const float mn = fmaxf(mrun, pm);
        const float corr = exp2f(mrun - mn);
        mrun = mn; lrun *= corr;
#pragma unroll
        for (int dc = 0; dc < 4; ++dc)
#pragma unroll
          for (int i = 0; i < 16; ++i) acc[dc][i] *= corr;
      }
#pragma unroll
      for (int i = 0; i < 16; ++i) scB[i] = exp2f(scB[i] - mrun);
      lrun += (((scB[0] + scB[1]) + (scB[2] + scB[3])) + ((scB[4] + scB[5]) + (scB[6] + scB[7]))) +
              (((scB[8] + scB[9]) + (scB[10] + scB[11])) + ((scB[12] + scB[13]) + (scB[14] + scB[15])));
      const unsigned wv0 = pk2(scB[0], scB[1]),   wv1 = pk2(scB[2], scB[3]);
      const unsigned wv2 = pk2(scB[4], scB[5]),   wv3 = pk2(scB[6], scB[7]);
      const unsigned wv4 = pk2(scB[8], scB[9]),   wv5 = pk2(scB[10], scB[11]);
      const unsigned wv6 = pk2(scB[12], scB[13]), wv7 = pk2(scB[14], scB[15]);
      auto r02 = __builtin_amdgcn_permlane32_swap(wv0, wv2, false, false);
      auto r13 = __builtin_amdgcn_permlane32_swap(wv1, wv3, false, false);
      auto r46 = __builtin_amdgcn_permlane32_swap(wv4, wv6, false, false);
      auto r57 = __builtin_amdgcn_permlane32_swap(wv5, wv7, false, false);
      const u32x4 pa0u = {r02[0], r13[0], r02[1], r13[1]};
      const u32x4 pa1u = {r46[0], r57[0], r46[1], r57[1]};
      const s16x8 pa0 = __builtin_bit_cast(s16x8, pa0u);
      const s16x8 pa1 = __builtin_bit_cast(s16x8, pa1u);
      __builtin_amdgcn_s_setprio(1);
#pragma unroll
      for (int dc = 0; dc < 4; ++dc) {
        const s16x8 vf = *(const s16x8*)&Vs[(dc * 32 + l31) * 64 + (((4 + h) ^ (l31 & 7)) << 3)];
        acc[dc] = __builtin_amdgcn_mfma_f32_32x32x16_bf16(vf, pa0, acc[dc], 0, 0, 0);
      }
#pragma unroll
      for (int dc = 0; dc < 4; ++dc) {
        const s16x8 vf = *(const s16x8*)&Vs[(dc * 32 + l31) * 64 + (((6 + h) ^ (l31 & 7)) << 3)];
        acc[dc] = __builtin_amdgcn_mfma_f32_32x32x16_bf16(vf, pa1, acc[dc], 0, 0, 0);
      }
      __builtin_amdgcn_s_setprio(0);
    }
    __syncthreads();  // drains vmcnt(0): next tile staged; all waves past cur
    cur ^= 1;
  }
  {
    auto rl = __builtin_amdgcn_permlane32_swap(__builtin_bit_cast(unsigned, lrun),
                                               __builtin_bit_cast(unsigned, lrun), false, false);
    lrun = asf(rl[0]) + asf(rl[1]);
  }
  const float inv = 1.0f / lrun;
  unsigned short* Op = ob + ((size_t)n * SS + qrow) * DD + dblk;
#pragma unroll
  for (int dc = 0; dc < 4; ++dc)
#pragma unroll
    for (int rg = 0; rg < 4; ++rg) {
      uint2 u;
      u.x = pk2(acc[dc][rg * 4 + 0] * inv, acc[dc][rg * 4 + 1] * inv);
      u.y = pk2(acc[dc][rg * 4 + 2] * inv, acc[dc][rg * 4 + 3] * inv);
      *(uint2*)(Op + dc * 32 + rg * 8 + h * 4) = u;
    }
}

// ---- fused proj + bias + residual ----
__global__ __launch_bounds__(256) void k_proj(const unsigned short* __restrict__ ob,
    const unsigned short* __restrict__ wpb, const float* __restrict__ bp,
    const float* __restrict__ x, float* __restrict__ out) {
  __shared__ __attribute__((aligned(16))) unsigned short As[128 * 32];
  __shared__ __attribute__((aligned(16))) unsigned short Bs[128 * 32];
  const int n = blockIdx.z;
  const int s0 = blockIdx.x * 128;
  const int c0 = blockIdx.y * 128;
  const int tid = threadIdx.x;
  const int lane = tid & 63, wid = tid >> 6;
  const int lo = lane & 15, hi = lane >> 4;
  const int wr = wid >> 1, wc = wid & 1;
  const unsigned short* On = ob + (size_t)n * SS * DD;
  f32x4 acc[4][4] = {};
  for (int k0 = 0; k0 < DD; k0 += 32) {
#pragma unroll
    for (int i = 0; i < 2; ++i) {
      const int seg = i * 256 + wid * 64 + lane;
      const int row = seg >> 2, c8 = seg & 3;
      GLOAD16(wpb + (size_t)(c0 + row) * DD + k0 + c8 * 8, As + (size_t)(i * 256 + wid * 64) * 8);
      GLOAD16(On + (size_t)(s0 + row) * DD + k0 + c8 * 8, Bs + (size_t)(i * 256 + wid * 64) * 8);
    }
    __syncthreads();
    s16x8 a[4], b[4];
#pragma unroll
    for (int mi = 0; mi < 4; ++mi)
      a[mi] = *(const s16x8*)&As[(wr * 64 + mi * 16 + lo) * 32 + hi * 8];
#pragma unroll
    for (int ni = 0; ni < 4; ++ni)
      b[ni] = *(const s16x8*)&Bs[(wc * 64 + ni * 16 + lo) * 32 + hi * 8];
#pragma unroll
    for (int mi = 0; mi < 4; ++mi)
#pragma unroll
      for (int ni = 0; ni < 4; ++ni)
        acc[mi][ni] = __builtin_amdgcn_mfma_f32_16x16x32_bf16(a[mi], b[ni], acc[mi][ni], 0, 0, 0);
    __syncthreads();
  }
#pragma unroll
  for (int mi = 0; mi < 4; ++mi) {
#pragma unroll
    for (int r = 0; r < 4; ++r) {
      const int c = c0 + wr * 64 + mi * 16 + hi * 4 + r;
      const float bpc = bp[c];
      const size_t base = ((size_t)n * CD + c) * SS;
#pragma unroll
      for (int ni = 0; ni < 4; ++ni) {
        const int s = s0 + wc * 64 + ni * 16 + lo;
        out[base + s] = acc[mi][ni][r] + bpc + x[base + s];
      }
    }
  }
}

extern "C" void kernel_launch(void* const* d_in, const int* in_sizes, int n_in,
                              void* d_out, int out_size, void* d_ws, size_t ws_size,
                              hipStream_t stream) {
  const float* x  = (const float*)d_in[0];
  const float* t  = (const float*)d_in[1];
  const float* Wt = (const float*)d_in[2];
  const float* bt = (const float*)d_in[3];
  const float* Wq = (const float*)d_in[4];
  const float* Wk = (const float*)d_in[5];
  const float* Wv = (const float*)d_in[6];
  const float* Wp = (const float*)d_in[7];
  const float* bp = (const float*)d_in[8];
  char* ws = (char*)d_ws;
  float* temb        = (float*)ws;                              // 32 KB
  unsigned short* wb = (unsigned short*)(ws + 32768);           // 512 KB (q,k,v,p)
  unsigned short* xb = (unsigned short*)(ws + 557056);          // 16 MB [n,s,c]
  unsigned short* qb = (unsigned short*)(ws + 17334272);        // 16 MB [n,s,d]
  unsigned short* kb = (unsigned short*)(ws + 34111488);        // 16 MB [n,s,d]
  unsigned short* vtb = (unsigned short*)(ws + 50888704);       // 16 MB [n,d,s]
  unsigned short* ob = (unsigned short*)(ws + 67665920);        // 16 MB [n,s,d]
  float* out = (float*)d_out;

  k_misc<<<1056, 256, 0, stream>>>(t, Wt, bt, temb, Wq, Wk, Wv, Wp, wb);
  k_addT<<<dim3(8, 32, 32), 256, 0, stream>>>(x, temb, xb);
  k_qkv<<<dim3(8, 2, 96), 256, 0, stream>>>(xb, wb, qb, kb, vtb);
  k_attn<<<256, 512, 0, stream>>>(qb, kb, vtb, ob);
  k_proj<<<dim3(8, 2, 32), 256, 0, stream>>>(ob, wb + 196608, bp, x, out);
}